// Round 5
// baseline (2250.561 us; speedup 1.0000x reference)
//
#include <hip/hip_runtime.h>

// N=64, T=512, D=H=512.
//   xw = x @ Wx + b   -> d_out (fp32), big MFMA GEMM
//   h_t = tanh(h_{t-1} @ Wh + xw_t) -> overwrites d_out in place
//
// rnn_scan v4 (round-4 lessons):
//  - Round-4 used 512 thr (2 waves/SIMD -> 256-reg cap) but needed ~260 regs:
//    weight array partially spilled -> ~2x slowdown. Now 256 thr, 4 waves,
//    1 wave/SIMD, 512 unified regs/wave: 12 kk of Wh in registers (384 regs,
//    AGPR-backed), 4 kk in 128 KB LDS. No spill, honest residency.
//  - LDS traffic/step: 64 A-frag b128 (4 waves x 16) + 128 W b128 ~= 2300 cy,
//    overlapped with MFMA floor 2483 cy (separate pipes).
//  - h double-buffered in LDS (2 x 16 KB), ONE raw s_barrier per step
//    (lgkmcnt(0) only -> global loads/stores stay in flight across it).
//  - xw for step t+1 prefetched into 32 regs during step t.
// LDS = 131072 (wlds) + 2*16384 (h) = 163840 B (160 KB exactly).

typedef __attribute__((ext_vector_type(8))) short short8;
typedef __attribute__((ext_vector_type(4))) float f32x4;

#define DIM 512
#define T_S 512

union Frag { uint4 v; short8 s; unsigned short u[8]; };

static __device__ __forceinline__ unsigned short f2bf(float f) {
  union { float f; unsigned u; } v;
  v.f = f;
  unsigned r = v.u + 0x7FFFu + ((v.u >> 16) & 1u);
  return (unsigned short)(r >> 16);
}

static __device__ __forceinline__ float fast_tanh(float s) {
  float e = __builtin_amdgcn_exp2f(2.885390082f * s);
  return 1.0f - 2.0f * __builtin_amdgcn_rcpf(e + 1.0f);
}

// ---------------------------------------------------------------------------
// Pack W (512x512 fp32) into bf16 MFMA B-fragments.
// Frag (kk, cc): lane l holds B[k=32kk+8(l>>4)+j][col=16cc+(l&15)], j=0..7,
// at dst[(kk*32+cc)*64 + lane].
// ---------------------------------------------------------------------------
__global__ __launch_bounds__(64) void prepack(const float* __restrict__ Wx,
                                              const float* __restrict__ Wh,
                                              uint4* __restrict__ wxb,
                                              uint4* __restrict__ whb) {
  int bid = blockIdx.x;
  int mat = bid >> 9;
  int idx = bid & 511;
  int kk = idx >> 5, cc = idx & 31;
  int lane = threadIdx.x;
  int lo = lane & 15, hi = lane >> 4;
  const float* src = mat ? Wh : Wx;
  uint4* dst = mat ? whb : wxb;
  int col = cc * 16 + lo;
  int kbase = kk * 32 + hi * 8;
  Frag fr;
#pragma unroll
  for (int j = 0; j < 8; ++j)
    fr.u[j] = f2bf(src[(size_t)(kbase + j) * DIM + col]);
  dst[(kk * 32 + cc) * 64 + lane] = fr.v;
}

// ---------------------------------------------------------------------------
// xw = x @ Wx + b -> out (fp32). M=32768, K=N=512. Unchanged.
// ---------------------------------------------------------------------------
__global__ __launch_bounds__(256) void gemm_xw(const float* __restrict__ x,
                                               const uint4* __restrict__ wxb,
                                               const float* __restrict__ bias,
                                               float* __restrict__ out) {
  int bid = blockIdx.x;
  int m = bid >> 2, nb = bid & 3;
  int wave = threadIdx.x >> 6, lane = threadIdx.x & 63;
  int lo = lane & 15, hi = lane >> 4;
  int rowbase = m * 64;
  int colbase = nb * 128 + wave * 32;

  f32x4 acc[4][2];
#pragma unroll
  for (int mi = 0; mi < 4; ++mi)
#pragma unroll
    for (int ni = 0; ni < 2; ++ni) acc[mi][ni] = (f32x4){0.f, 0.f, 0.f, 0.f};

  for (int kk = 0; kk < 16; ++kk) {
    short8 afrag[4];
#pragma unroll
    for (int mi = 0; mi < 4; ++mi) {
      const float* ap = x + (size_t)(rowbase + mi * 16 + lo) * DIM + kk * 32 + hi * 8;
      float4 f0 = *(const float4*)ap;
      float4 f1 = *(const float4*)(ap + 4);
      Frag a;
      a.u[0] = f2bf(f0.x); a.u[1] = f2bf(f0.y); a.u[2] = f2bf(f0.z); a.u[3] = f2bf(f0.w);
      a.u[4] = f2bf(f1.x); a.u[5] = f2bf(f1.y); a.u[6] = f2bf(f1.z); a.u[7] = f2bf(f1.w);
      afrag[mi] = a.s;
    }
#pragma unroll
    for (int ni = 0; ni < 2; ++ni) {
      int cc = nb * 8 + wave * 2 + ni;
      Frag b;
      b.v = wxb[(kk * 32 + cc) * 64 + lane];
#pragma unroll
      for (int mi = 0; mi < 4; ++mi)
        acc[mi][ni] = __builtin_amdgcn_mfma_f32_16x16x32_bf16(afrag[mi], b.s, acc[mi][ni], 0, 0, 0);
    }
  }
#pragma unroll
  for (int ni = 0; ni < 2; ++ni) {
    int col = colbase + ni * 16 + lo;
    float bv = bias[col];
#pragma unroll
    for (int mi = 0; mi < 4; ++mi)
#pragma unroll
      for (int r = 0; r < 4; ++r) {
        int row = rowbase + mi * 16 + hi * 4 + r;
        out[(size_t)row * DIM + col] = acc[mi][ni][r] + bv;
      }
  }
}

// ---------------------------------------------------------------------------
// Recurrent scan v4. grid = 4 blocks x 256 thr (4 waves, 1/SIMD, 512 regs).
// Block g: batch rows [16g,16g+16), all 512 cols. Wave w: cols [128w,128w+128)
// (8 col-tiles cc = 8w..8w+7).
// ---------------------------------------------------------------------------
__shared__ uint4 wlds[4][32][64];          // 128 KB: Wh kk=12..15  [kk-12][cc][lane]
__shared__ unsigned short hA[16 * 512];    // 16 KB ping
__shared__ unsigned short hB[16 * 512];    // 16 KB pong

static __device__ __forceinline__ uint4 ld_h(const unsigned short* buf, int lo,
                                             int kk, int hi) {
  // A-frag: row=lo, k0 = kk*32 + hi*8 -> 16 B, XOR-swizzled by row
  int byte = lo * 1024 + ((kk * 64 + hi * 16) ^ ((lo & 7) << 4));
  return *(const uint4*)((const char*)buf + byte);
}

static __device__ __forceinline__ void st_h(unsigned short* buf, int row, int col,
                                            unsigned short v) {
  int byte = row * 1024 + ((col * 2) ^ ((row & 7) << 4));
  *(unsigned short*)((char*)buf + byte) = v;
}

static __device__ __forceinline__ void step_body(
    const unsigned short* RD, unsigned short* WR, int t, int g, int w, int lane,
    int lo, int hi, const uint4 (&bw)[12][8], float (&xwv)[32],
    float* __restrict__ out) {
  f32x4 acc[8];
#pragma unroll
  for (int i = 0; i < 8; ++i) acc[i] = (f32x4){0.f, 0.f, 0.f, 0.f};

  // kk 0..11: VGPR/AGPR-resident weights
#pragma unroll
  for (int kk = 0; kk < 12; ++kk) {
    Frag a; a.v = ld_h(RD, lo, kk, hi);
#pragma unroll
    for (int i = 0; i < 8; ++i) {
      Frag b; b.v = bw[kk][i];
      acc[i] = __builtin_amdgcn_mfma_f32_16x16x32_bf16(a.s, b.s, acc[i], 0, 0, 0);
    }
  }
  // kk 12..15: LDS-resident weights (lane-contiguous uint4, conflict-free)
#pragma unroll
  for (int kk = 12; kk < 16; ++kk) {
    Frag a; a.v = ld_h(RD, lo, kk, hi);
#pragma unroll
    for (int i = 0; i < 8; ++i) {
      Frag b; b.v = wlds[kk - 12][w * 8 + i][lane];
      acc[i] = __builtin_amdgcn_mfma_f32_16x16x32_bf16(a.s, b.s, acc[i], 0, 0, 0);
    }
  }

  // epilogue: row = 4*hi + r, col = 128w + 16i + lo
#pragma unroll
  for (int r = 0; r < 4; ++r) {
    float* orow = out + (((size_t)(g * 16 + hi * 4 + r) * T_S + t) * DIM) + w * 128 + lo;
#pragma unroll
    for (int i = 0; i < 8; ++i) {
      float sv = acc[i][r] + xwv[r * 8 + i];
      float h = fast_tanh(sv);
      orow[i * 16] = h;
      st_h(WR, hi * 4 + r, w * 128 + i * 16 + lo, f2bf(h));
    }
  }

  // prefetch xw for step t+1 (consumed next epilogue, a full step later)
  int tn = (t < T_S - 1) ? (t + 1) : (T_S - 1);
#pragma unroll
  for (int r = 0; r < 4; ++r) {
    const float* lrow = out + (((size_t)(g * 16 + hi * 4 + r) * T_S + tn) * DIM) + w * 128 + lo;
#pragma unroll
    for (int i = 0; i < 8; ++i) xwv[r * 8 + i] = lrow[i * 16];
  }

  // one barrier per step: LDS h-writes visible; no vmem drain (raw s_barrier)
  asm volatile("s_waitcnt lgkmcnt(0)" ::: "memory");
  __builtin_amdgcn_sched_barrier(0);
  __builtin_amdgcn_s_barrier();
  __builtin_amdgcn_sched_barrier(0);
}

__global__ __launch_bounds__(256, 1) void rnn_scan(const float* __restrict__ h0,
                                                   const uint4* __restrict__ whb,
                                                   float* __restrict__ out) {
  int g = blockIdx.x;
  int w = threadIdx.x >> 6, lane = threadIdx.x & 63;
  int lo = lane & 15, hi = lane >> 4;

  // register-resident Wh: kk 0..11 x this wave's 8 col-tiles = 384 regs
  uint4 bw[12][8];
#pragma unroll
  for (int kk = 0; kk < 12; ++kk)
#pragma unroll
    for (int i = 0; i < 8; ++i)
      bw[kk][i] = whb[(kk * 32 + (w * 8 + i)) * 64 + lane];

  // LDS-resident Wh: kk 12..15, all 32 cc (coalesced cooperative stage)
#pragma unroll
  for (int e = 0; e < 32; ++e) {
    int idx = e * 256 + threadIdx.x;
    int s = idx >> 11, rem = idx & 2047;
    wlds[s][rem >> 6][rem & 63] = whb[((12 + s) * 32 + (rem >> 6)) * 64 + (rem & 63)];
  }

  // h_0 into ping buffer (bf16, swizzled)
#pragma unroll
  for (int r = 0; r < 4; ++r)
#pragma unroll
    for (int i = 0; i < 8; ++i) {
      int row = hi * 4 + r;
      int col = w * 128 + i * 16 + lo;
      st_h(hA, row, col, f2bf(h0[(size_t)(g * 16 + row) * DIM + col]));
    }

  // prime xw for t=0
  float xwv[32];
#pragma unroll
  for (int r = 0; r < 4; ++r)
#pragma unroll
    for (int i = 0; i < 8; ++i)
      xwv[r * 8 + i] =
          out[((size_t)(g * 16 + hi * 4 + r) * T_S + 0) * DIM + w * 128 + i * 16 + lo];

  __syncthreads();  // heavy barrier once before the loop

#pragma unroll 1
  for (int t = 0; t < T_S; t += 2) {
    step_body(hA, hB, t,     g, w, lane, lo, hi, bw, xwv, out);
    step_body(hB, hA, t + 1, g, w, lane, lo, hi, bw, xwv, out);
  }
}

// ---------------------------------------------------------------------------
extern "C" void kernel_launch(void* const* d_in, const int* in_sizes, int n_in,
                              void* d_out, int out_size, void* d_ws, size_t ws_size,
                              hipStream_t stream) {
  const float* x  = (const float*)d_in[0];
  const float* h0 = (const float*)d_in[1];
  const float* Wx = (const float*)d_in[2];
  const float* Wh = (const float*)d_in[3];
  const float* b  = (const float*)d_in[4];
  float* out = (float*)d_out;

  char* ws = (char*)d_ws;
  uint4* whb = (uint4*)ws;                  // 512 KB
  uint4* wxb = (uint4*)(ws + 524288);       // 512 KB

  prepack<<<1024, 64, 0, stream>>>(Wx, Wh, wxb, whb);
  gemm_xw<<<2048, 256, 0, stream>>>(x, wxb, b, out);
  rnn_scan<<<4, 256, 0, stream>>>(h0, whb, out);
}

// Round 6
// 2172.576 us; speedup vs baseline: 1.0359x; 1.0359x over previous
//
#include <hip/hip_runtime.h>

// N=64, T=512, D=H=512.
//   xw = x @ Wx + b   -> d_out (fp32), big MFMA GEMM
//   h_t = tanh(h_{t-1} @ Wh + xw_t) -> overwrites d_out in place
//
// rnn_scan v5 (round-5 lesson: step time identical across two register
// structures -> bottleneck is exposed VMEM latency, not residency):
//  - acc initialized FROM xw (frees xwv at step start; fp-order change ~ulp)
//  - xw(t+1) loads issued at TOP of step, before MFMA: VMEM queue becomes
//    [loads, stores] so the next-step wait is vmcnt(32), not a full drain;
//    stores retire under the MFMA phase.
//  - running row-pointers (+DIM/step) with imm column offsets: no per-step
//    64-bit address rebuild.
//  - Wh: 12 kk in 384 regs (256 AGPR + 128 VGPR), 4 kk in 128 KB LDS.
//  - h double-buffered in LDS (2 x 16 KB), ONE raw s_barrier per step
//    (lgkmcnt(0) only; global traffic stays in flight across it).
// LDS = 131072 + 2*16384 = 163840 B (160 KB exactly).

typedef __attribute__((ext_vector_type(8))) short short8;
typedef __attribute__((ext_vector_type(4))) float f32x4;

#define DIM 512
#define T_S 512

union Frag { uint4 v; short8 s; unsigned short u[8]; };

static __device__ __forceinline__ unsigned short f2bf(float f) {
  union { float f; unsigned u; } v;
  v.f = f;
  unsigned r = v.u + 0x7FFFu + ((v.u >> 16) & 1u);
  return (unsigned short)(r >> 16);
}

static __device__ __forceinline__ float fast_tanh(float s) {
  float e = __builtin_amdgcn_exp2f(2.885390082f * s);
  return 1.0f - 2.0f * __builtin_amdgcn_rcpf(e + 1.0f);
}

// ---------------------------------------------------------------------------
// Pack W (512x512 fp32) into bf16 MFMA B-fragments.
// Frag (kk, cc): lane l holds B[k=32kk+8(l>>4)+j][col=16cc+(l&15)], j=0..7,
// at dst[(kk*32+cc)*64 + lane].
// ---------------------------------------------------------------------------
__global__ __launch_bounds__(64) void prepack(const float* __restrict__ Wx,
                                              const float* __restrict__ Wh,
                                              uint4* __restrict__ wxb,
                                              uint4* __restrict__ whb) {
  int bid = blockIdx.x;
  int mat = bid >> 9;
  int idx = bid & 511;
  int kk = idx >> 5, cc = idx & 31;
  int lane = threadIdx.x;
  int lo = lane & 15, hi = lane >> 4;
  const float* src = mat ? Wh : Wx;
  uint4* dst = mat ? whb : wxb;
  int col = cc * 16 + lo;
  int kbase = kk * 32 + hi * 8;
  Frag fr;
#pragma unroll
  for (int j = 0; j < 8; ++j)
    fr.u[j] = f2bf(src[(size_t)(kbase + j) * DIM + col]);
  dst[(kk * 32 + cc) * 64 + lane] = fr.v;
}

// ---------------------------------------------------------------------------
// xw = x @ Wx + b -> out (fp32). M=32768, K=N=512. Unchanged.
// ---------------------------------------------------------------------------
__global__ __launch_bounds__(256) void gemm_xw(const float* __restrict__ x,
                                               const uint4* __restrict__ wxb,
                                               const float* __restrict__ bias,
                                               float* __restrict__ out) {
  int bid = blockIdx.x;
  int m = bid >> 2, nb = bid & 3;
  int wave = threadIdx.x >> 6, lane = threadIdx.x & 63;
  int lo = lane & 15, hi = lane >> 4;
  int rowbase = m * 64;
  int colbase = nb * 128 + wave * 32;

  f32x4 acc[4][2];
#pragma unroll
  for (int mi = 0; mi < 4; ++mi)
#pragma unroll
    for (int ni = 0; ni < 2; ++ni) acc[mi][ni] = (f32x4){0.f, 0.f, 0.f, 0.f};

  for (int kk = 0; kk < 16; ++kk) {
    short8 afrag[4];
#pragma unroll
    for (int mi = 0; mi < 4; ++mi) {
      const float* ap = x + (size_t)(rowbase + mi * 16 + lo) * DIM + kk * 32 + hi * 8;
      float4 f0 = *(const float4*)ap;
      float4 f1 = *(const float4*)(ap + 4);
      Frag a;
      a.u[0] = f2bf(f0.x); a.u[1] = f2bf(f0.y); a.u[2] = f2bf(f0.z); a.u[3] = f2bf(f0.w);
      a.u[4] = f2bf(f1.x); a.u[5] = f2bf(f1.y); a.u[6] = f2bf(f1.z); a.u[7] = f2bf(f1.w);
      afrag[mi] = a.s;
    }
#pragma unroll
    for (int ni = 0; ni < 2; ++ni) {
      int cc = nb * 8 + wave * 2 + ni;
      Frag b;
      b.v = wxb[(kk * 32 + cc) * 64 + lane];
#pragma unroll
      for (int mi = 0; mi < 4; ++mi)
        acc[mi][ni] = __builtin_amdgcn_mfma_f32_16x16x32_bf16(afrag[mi], b.s, acc[mi][ni], 0, 0, 0);
    }
  }
#pragma unroll
  for (int ni = 0; ni < 2; ++ni) {
    int col = colbase + ni * 16 + lo;
    float bv = bias[col];
#pragma unroll
    for (int mi = 0; mi < 4; ++mi)
#pragma unroll
      for (int r = 0; r < 4; ++r) {
        int row = rowbase + mi * 16 + hi * 4 + r;
        out[(size_t)row * DIM + col] = acc[mi][ni][r] + bv;
      }
  }
}

// ---------------------------------------------------------------------------
// Recurrent scan v5. grid = 4 blocks x 256 thr (4 waves, 1/SIMD).
// Block g: batch rows [16g,16g+16), all 512 cols. Wave w: cols [128w,128w+128).
// ---------------------------------------------------------------------------
__shared__ uint4 wlds[4][32][64];          // 128 KB: Wh kk=12..15  [kk-12][cc][lane]
__shared__ unsigned short hA[16 * 512];    // 16 KB ping
__shared__ unsigned short hB[16 * 512];    // 16 KB pong

static __device__ __forceinline__ uint4 ld_h(const unsigned short* buf, int lo,
                                             int kk, int hi) {
  // A-frag: row=lo, k0 = kk*32 + hi*8 -> 16 B, XOR-swizzled by row
  int byte = lo * 1024 + ((kk * 64 + hi * 16) ^ ((lo & 7) << 4));
  return *(const uint4*)((const char*)buf + byte);
}

static __device__ __forceinline__ void st_h(unsigned short* buf, int row, int col,
                                            unsigned short v) {
  int byte = row * 1024 + ((col * 2) ^ ((row & 7) << 4));
  *(unsigned short*)((char*)buf + byte) = v;
}

static __device__ __forceinline__ void step_body(
    const unsigned short* RD, unsigned short* WR, int t, int w, int lane,
    int lo, int hi, const uint4 (&bw)[12][8], float (&xwv)[32],
    float* (&pr)[4]) {
  // acc starts at xw (frees xwv immediately; fp-order change is ~1 ulp)
  f32x4 acc[8];
#pragma unroll
  for (int i = 0; i < 8; ++i)
#pragma unroll
    for (int r = 0; r < 4; ++r) acc[i][r] = xwv[r * 8 + i];

  // issue xw(t+1) loads NOW (before MFMA): ~2500 cy to complete, fully hidden.
  // t=511 clamps to re-reading row 511 (values discarded).
  const int off = (t < T_S - 1) ? DIM : 0;
#pragma unroll
  for (int r = 0; r < 4; ++r)
#pragma unroll
    for (int i = 0; i < 8; ++i) xwv[r * 8 + i] = pr[r][off + i * 16];

  // kk 0..11: register-resident weights
#pragma unroll
  for (int kk = 0; kk < 12; ++kk) {
    Frag a; a.v = ld_h(RD, lo, kk, hi);
#pragma unroll
    for (int i = 0; i < 8; ++i) {
      Frag b; b.v = bw[kk][i];
      acc[i] = __builtin_amdgcn_mfma_f32_16x16x32_bf16(a.s, b.s, acc[i], 0, 0, 0);
    }
  }
  // kk 12..15: LDS-resident weights (lane-contiguous uint4, conflict-free)
#pragma unroll
  for (int kk = 12; kk < 16; ++kk) {
    Frag a; a.v = ld_h(RD, lo, kk, hi);
#pragma unroll
    for (int i = 0; i < 8; ++i) {
      Frag b; b.v = wlds[kk - 12][w * 8 + i][lane];
      acc[i] = __builtin_amdgcn_mfma_f32_16x16x32_bf16(a.s, b.s, acc[i], 0, 0, 0);
    }
  }

  // epilogue: row = 4*hi + r, col = 128w + 16i + lo
#pragma unroll
  for (int r = 0; r < 4; ++r) {
#pragma unroll
    for (int i = 0; i < 8; ++i) {
      float h = fast_tanh(acc[i][r]);
      st_h(WR, hi * 4 + r, w * 128 + i * 16 + lo, f2bf(h));
      pr[r][i * 16] = h;  // global store of h_t (row t); drains under next MFMA
    }
  }
#pragma unroll
  for (int r = 0; r < 4; ++r) pr[r] += DIM;

  // one barrier per step: LDS h-writes visible; no vmem drain (raw s_barrier)
  asm volatile("s_waitcnt lgkmcnt(0)" ::: "memory");
  __builtin_amdgcn_sched_barrier(0);
  __builtin_amdgcn_s_barrier();
  __builtin_amdgcn_sched_barrier(0);
}

__global__ __launch_bounds__(256, 1) void rnn_scan(const float* __restrict__ h0,
                                                   const uint4* __restrict__ whb,
                                                   float* __restrict__ out) {
  int g = blockIdx.x;
  int w = threadIdx.x >> 6, lane = threadIdx.x & 63;
  int lo = lane & 15, hi = lane >> 4;

  // register-resident Wh: kk 0..11 x this wave's 8 col-tiles = 384 regs
  uint4 bw[12][8];
#pragma unroll
  for (int kk = 0; kk < 12; ++kk)
#pragma unroll
    for (int i = 0; i < 8; ++i)
      bw[kk][i] = whb[(kk * 32 + (w * 8 + i)) * 64 + lane];

  // LDS-resident Wh: kk 12..15, all 32 cc (coalesced cooperative stage)
#pragma unroll
  for (int e = 0; e < 32; ++e) {
    int idx = e * 256 + threadIdx.x;
    int s = idx >> 11, rem = idx & 2047;
    wlds[s][rem >> 6][rem & 63] = whb[((12 + s) * 32 + (rem >> 6)) * 64 + (rem & 63)];
  }

  // h_0 into ping buffer (bf16, swizzled)
#pragma unroll
  for (int r = 0; r < 4; ++r)
#pragma unroll
    for (int i = 0; i < 8; ++i) {
      int row = hi * 4 + r;
      int col = w * 128 + i * 16 + lo;
      st_h(hA, row, col, f2bf(h0[(size_t)(g * 16 + row) * DIM + col]));
    }

  // running row-pointers: pr[r] -> out[n = 16g+4hi+r][t=0][col base]
  float* pr[4];
#pragma unroll
  for (int r = 0; r < 4; ++r)
    pr[r] = out + ((size_t)(g * 16 + hi * 4 + r) * T_S) * DIM + w * 128 + lo;

  // prime xw for t=0
  float xwv[32];
#pragma unroll
  for (int r = 0; r < 4; ++r)
#pragma unroll
    for (int i = 0; i < 8; ++i) xwv[r * 8 + i] = pr[r][i * 16];

  __syncthreads();  // heavy barrier once before the loop

#pragma unroll 1
  for (int t = 0; t < T_S; t += 2) {
    step_body(hA, hB, t,     w, lane, lo, hi, bw, xwv, pr);
    step_body(hB, hA, t + 1, w, lane, lo, hi, bw, xwv, pr);
  }
}

// ---------------------------------------------------------------------------
extern "C" void kernel_launch(void* const* d_in, const int* in_sizes, int n_in,
                              void* d_out, int out_size, void* d_ws, size_t ws_size,
                              hipStream_t stream) {
  const float* x  = (const float*)d_in[0];
  const float* h0 = (const float*)d_in[1];
  const float* Wx = (const float*)d_in[2];
  const float* Wh = (const float*)d_in[3];
  const float* b  = (const float*)d_in[4];
  float* out = (float*)d_out;

  char* ws = (char*)d_ws;
  uint4* whb = (uint4*)ws;                  // 512 KB
  uint4* wxb = (uint4*)(ws + 524288);       // 512 KB

  prepack<<<1024, 64, 0, stream>>>(Wx, Wh, wxb, whb);
  gemm_xw<<<2048, 256, 0, stream>>>(x, wxb, b, out);
  rnn_scan<<<4, 256, 0, stream>>>(h0, whb, out);
}

// Round 7
// 1827.641 us; speedup vs baseline: 1.2314x; 1.1887x over previous
//
#include <hip/hip_runtime.h>

// N=64, T=512, D=H=512.
//   xw = x @ Wx + b   -> d_out (fp32), big MFMA GEMM
//   h_t = tanh(h_{t-1} @ Wh + xw_t) -> overwrites d_out in place
//
// rnn_scan v6 (round-6 lesson: ~2000cy/step VALU + waits from scalar epilogue):
//  SWAPPED-OPERAND MFMA: D = mfma(A=Wh_frag, B=h_frag) -> D[c][n], lane owns
//  batch row n=lo and 4 CONSECUTIVE cols per acc group. So:
//   - xw loads / h stores: 8x dwordx4 per step (was 64 scalar ops)
//   - LDS h writes: 8x ds_write_b64 (was 32x b16); f2bf via v_cvt_pk_bf16_f32
//   - LDS addresses: 12 loop-invariant VGPR bases + imm offsets (the +512,
//     +16384, +128 deltas don't collide with XOR-swizzle bits 4..6)
//  Weight frags unchanged (A/B frag layouts symmetric); kk order unchanged.
//  Wh: 12 kk in 384 regs + 4 kk in 128 KB LDS; h ping-pong 2x16 KB; one raw
//  s_barrier + lgkmcnt(0) per step. LDS = 160 KB exactly.

typedef __attribute__((ext_vector_type(8))) short short8;
typedef __attribute__((ext_vector_type(4))) float f32x4;

#define DIM 512
#define T_S 512

union Frag { uint4 v; short8 s; unsigned short u[8]; };

static __device__ __forceinline__ unsigned short f2bf(float f) {
  union { float f; unsigned u; } v;
  v.f = f;
  unsigned r = v.u + 0x7FFFu + ((v.u >> 16) & 1u);
  return (unsigned short)(r >> 16);
}

static __device__ __forceinline__ unsigned cvt_pk_bf16(float a, float b) {
  unsigned r;
  asm("v_cvt_pk_bf16_f32 %0, %1, %2" : "=v"(r) : "v"(a), "v"(b));
  return r;  // lo16 = bf16(a), hi16 = bf16(b), RNE
}

static __device__ __forceinline__ float fast_tanh(float s) {
  float e = __builtin_amdgcn_exp2f(2.885390082f * s);
  return 1.0f - 2.0f * __builtin_amdgcn_rcpf(e + 1.0f);
}

// ---------------------------------------------------------------------------
// Pack W (512x512 fp32) into bf16 MFMA fragments (A/B-symmetric layout).
// Frag (kk, cc): lane l holds W[k=32kk+8(l>>4)+j][col=16cc+(l&15)], j=0..7,
// at dst[(kk*32+cc)*64 + lane].
// ---------------------------------------------------------------------------
__global__ __launch_bounds__(64) void prepack(const float* __restrict__ Wx,
                                              const float* __restrict__ Wh,
                                              uint4* __restrict__ wxb,
                                              uint4* __restrict__ whb) {
  int bid = blockIdx.x;
  int mat = bid >> 9;
  int idx = bid & 511;
  int kk = idx >> 5, cc = idx & 31;
  int lane = threadIdx.x;
  int lo = lane & 15, hi = lane >> 4;
  const float* src = mat ? Wh : Wx;
  uint4* dst = mat ? whb : wxb;
  int col = cc * 16 + lo;
  int kbase = kk * 32 + hi * 8;
  Frag fr;
#pragma unroll
  for (int j = 0; j < 8; ++j)
    fr.u[j] = f2bf(src[(size_t)(kbase + j) * DIM + col]);
  dst[(kk * 32 + cc) * 64 + lane] = fr.v;
}

// ---------------------------------------------------------------------------
// xw = x @ Wx + b -> out (fp32). M=32768, K=N=512. Unchanged.
// ---------------------------------------------------------------------------
__global__ __launch_bounds__(256) void gemm_xw(const float* __restrict__ x,
                                               const uint4* __restrict__ wxb,
                                               const float* __restrict__ bias,
                                               float* __restrict__ out) {
  int bid = blockIdx.x;
  int m = bid >> 2, nb = bid & 3;
  int wave = threadIdx.x >> 6, lane = threadIdx.x & 63;
  int lo = lane & 15, hi = lane >> 4;
  int rowbase = m * 64;
  int colbase = nb * 128 + wave * 32;

  f32x4 acc[4][2];
#pragma unroll
  for (int mi = 0; mi < 4; ++mi)
#pragma unroll
    for (int ni = 0; ni < 2; ++ni) acc[mi][ni] = (f32x4){0.f, 0.f, 0.f, 0.f};

  for (int kk = 0; kk < 16; ++kk) {
    short8 afrag[4];
#pragma unroll
    for (int mi = 0; mi < 4; ++mi) {
      const float* ap = x + (size_t)(rowbase + mi * 16 + lo) * DIM + kk * 32 + hi * 8;
      float4 f0 = *(const float4*)ap;
      float4 f1 = *(const float4*)(ap + 4);
      Frag a;
      a.u[0] = f2bf(f0.x); a.u[1] = f2bf(f0.y); a.u[2] = f2bf(f0.z); a.u[3] = f2bf(f0.w);
      a.u[4] = f2bf(f1.x); a.u[5] = f2bf(f1.y); a.u[6] = f2bf(f1.z); a.u[7] = f2bf(f1.w);
      afrag[mi] = a.s;
    }
#pragma unroll
    for (int ni = 0; ni < 2; ++ni) {
      int cc = nb * 8 + wave * 2 + ni;
      Frag b;
      b.v = wxb[(kk * 32 + cc) * 64 + lane];
#pragma unroll
      for (int mi = 0; mi < 4; ++mi)
        acc[mi][ni] = __builtin_amdgcn_mfma_f32_16x16x32_bf16(afrag[mi], b.s, acc[mi][ni], 0, 0, 0);
    }
  }
#pragma unroll
  for (int ni = 0; ni < 2; ++ni) {
    int col = colbase + ni * 16 + lo;
    float bv = bias[col];
#pragma unroll
    for (int mi = 0; mi < 4; ++mi)
#pragma unroll
      for (int r = 0; r < 4; ++r) {
        int row = rowbase + mi * 16 + hi * 4 + r;
        out[(size_t)row * DIM + col] = acc[mi][ni][r] + bv;
      }
  }
}

// ---------------------------------------------------------------------------
// Recurrent scan v6. grid = 4 blocks x 256 thr (4 waves, 1/SIMD).
// Block g: batch rows [16g,16g+16), all 512 cols. Wave w: cols [128w,128w+128).
// h in LDS as [buf][n][k] bf16, XOR-swizzled: byte = n*1024 + ((k*2)^((n&7)<<4)).
// ---------------------------------------------------------------------------
__shared__ uint4 wlds[4][32][64];             // 128 KB: Wh kk=12..15
__shared__ unsigned short hbuf2[2][16 * 512]; // 32 KB ping/pong

template <int BUF>
static __device__ __forceinline__ void step_body(
    int t, int w, int lane, const uint4 (&bw)[12][8],
    const uint4* const (&rdp)[8], uint2* const (&wrp)[4],
    float (&xwv)[32], float*& gp) {
  // acc starts at xw (lane: n=lo, cols 16(8w+i)+4hi+r)
  f32x4 acc[8];
#pragma unroll
  for (int i = 0; i < 8; ++i)
    acc[i] = (f32x4){xwv[i * 4 + 0], xwv[i * 4 + 1], xwv[i * 4 + 2], xwv[i * 4 + 3]};

  // prefetch xw(t+1): 8x dwordx4, issued before MFMA phase
  const float* lp = gp + ((t < T_S - 1) ? DIM : 0);
#pragma unroll
  for (int i = 0; i < 8; ++i) {
    float4 f = *(const float4*)(lp + i * 16);
    xwv[i * 4 + 0] = f.x; xwv[i * 4 + 1] = f.y;
    xwv[i * 4 + 2] = f.z; xwv[i * 4 + 3] = f.w;
  }

  // kk 0..11: register-resident weights as A; h frag as B (imm-offset reads)
#pragma unroll
  for (int kk = 0; kk < 12; ++kk) {
    Frag hf; hf.v = rdp[kk & 7][((kk & 8) ? 32 : 0) + BUF * 1024];
#pragma unroll
    for (int i = 0; i < 8; ++i) {
      Frag a; a.v = bw[kk][i];
      acc[i] = __builtin_amdgcn_mfma_f32_16x16x32_bf16(a.s, hf.s, acc[i], 0, 0, 0);
    }
  }
  // kk 12..15: LDS-resident weights
#pragma unroll
  for (int kk = 12; kk < 16; ++kk) {
    Frag hf; hf.v = rdp[kk & 7][32 + BUF * 1024];
#pragma unroll
    for (int i = 0; i < 8; ++i) {
      Frag a; a.v = wlds[kk - 12][w * 8 + i][lane];
      acc[i] = __builtin_amdgcn_mfma_f32_16x16x32_bf16(a.s, hf.s, acc[i], 0, 0, 0);
    }
  }

  // epilogue: lane owns n=lo, 4 consecutive cols per acc group
#pragma unroll
  for (int i = 0; i < 8; ++i) {
    float h0 = fast_tanh(acc[i][0]);
    float h1 = fast_tanh(acc[i][1]);
    float h2 = fast_tanh(acc[i][2]);
    float h3 = fast_tanh(acc[i][3]);
    *(float4*)(gp + i * 16) = (float4){h0, h1, h2, h3};   // out row n, 16B
    uint2 u;
    u.x = cvt_pk_bf16(h0, h1);
    u.y = cvt_pk_bf16(h2, h3);
    wrp[i & 3][(i >> 2) * 16 + (BUF ^ 1) * 2048] = u;     // ds_write_b64
  }
  gp += DIM;

  // one barrier per step: LDS h-writes visible; no vmem drain
  asm volatile("s_waitcnt lgkmcnt(0)" ::: "memory");
  __builtin_amdgcn_sched_barrier(0);
  __builtin_amdgcn_s_barrier();
  __builtin_amdgcn_sched_barrier(0);
}

__global__ __launch_bounds__(256, 1) void rnn_scan(const float* __restrict__ h0,
                                                   const uint4* __restrict__ whb,
                                                   float* __restrict__ out) {
  int g = blockIdx.x;
  int w = threadIdx.x >> 6, lane = threadIdx.x & 63;
  int lo = lane & 15, hi = lane >> 4;
  int msk = (lo & 7) << 4;

  // register-resident Wh: kk 0..11 x this wave's 8 col-tiles = 384 regs
  uint4 bw[12][8];
#pragma unroll
  for (int kk = 0; kk < 12; ++kk)
#pragma unroll
    for (int i = 0; i < 8; ++i)
      bw[kk][i] = whb[(kk * 32 + (w * 8 + i)) * 64 + lane];

  // LDS-resident Wh: kk 12..15, all 32 cc (coalesced cooperative stage)
#pragma unroll
  for (int e = 0; e < 32; ++e) {
    int idx = e * 256 + threadIdx.x;
    int s = idx >> 11, rem = idx & 2047;
    wlds[s][rem >> 6][rem & 63] = whb[((12 + s) * 32 + (rem >> 6)) * 64 + (rem & 63)];
  }

  // loop-invariant LDS addresses (buffer 0 bases; +16384 via imm for buffer 1)
  // read (B=h frag): byte = lo*1024 + ((kk*64 + hi*16) ^ msk), kk=0..7
  const uint4* rdp[8];
#pragma unroll
  for (int kk = 0; kk < 8; ++kk)
    rdp[kk] = (const uint4*)((const char*)hbuf2 + lo * 1024 + ((kk * 64 + hi * 16) ^ msk));
  // write: byte = lo*1024 + (((128w + 16i + 4hi)*2) ^ msk), i=0..3 bases
  uint2* wrp[4];
#pragma unroll
  for (int i = 0; i < 4; ++i)
    wrp[i] = (uint2*)((char*)hbuf2 + lo * 1024 + ((256 * w + 32 * i + 8 * hi) ^ msk));

  // h_0 into buffer 0: lane loads h0[n=lo][c..c+3], packs, b64-writes
#pragma unroll
  for (int i = 0; i < 8; ++i) {
    const float* hp = h0 + (size_t)(g * 16 + lo) * DIM + w * 128 + i * 16 + hi * 4;
    float4 f = *(const float4*)hp;
    uint2 u;
    u.x = (unsigned)f2bf(f.x) | ((unsigned)f2bf(f.y) << 16);
    u.y = (unsigned)f2bf(f.z) | ((unsigned)f2bf(f.w) << 16);
    wrp[i & 3][(i >> 2) * 16] = u;
  }

  // running global pointer: lane -> out[n=16g+lo][t=0][128w + 4hi]
  float* gp = out + ((size_t)(g * 16 + lo) * T_S) * DIM + w * 128 + hi * 4;

  // prime xw for t=0
  float xwv[32];
#pragma unroll
  for (int i = 0; i < 8; ++i) {
    float4 f = *(const float4*)(gp + i * 16);
    xwv[i * 4 + 0] = f.x; xwv[i * 4 + 1] = f.y;
    xwv[i * 4 + 2] = f.z; xwv[i * 4 + 3] = f.w;
  }

  __syncthreads();  // heavy barrier once before the loop

#pragma unroll 1
  for (int t = 0; t < T_S; t += 2) {
    step_body<0>(t,     w, lane, bw, rdp, wrp, xwv, gp);
    step_body<1>(t + 1, w, lane, bw, rdp, wrp, xwv, gp);
  }
}

// ---------------------------------------------------------------------------
extern "C" void kernel_launch(void* const* d_in, const int* in_sizes, int n_in,
                              void* d_out, int out_size, void* d_ws, size_t ws_size,
                              hipStream_t stream) {
  const float* x  = (const float*)d_in[0];
  const float* h0 = (const float*)d_in[1];
  const float* Wx = (const float*)d_in[2];
  const float* Wh = (const float*)d_in[3];
  const float* b  = (const float*)d_in[4];
  float* out = (float*)d_out;

  char* ws = (char*)d_ws;
  uint4* whb = (uint4*)ws;                  // 512 KB
  uint4* wxb = (uint4*)(ws + 524288);       // 512 KB

  prepack<<<1024, 64, 0, stream>>>(Wx, Wh, wxb, whb);
  gemm_xw<<<2048, 256, 0, stream>>>(x, wxb, b, out);
  rnn_scan<<<4, 256, 0, stream>>>(h0, whb, out);
}

// Round 8
// 1200.727 us; speedup vs baseline: 1.8743x; 1.5221x over previous
//
#include <hip/hip_runtime.h>

// N=64, T=512, D=H=512.
//   xw = x @ Wx + b   -> d_out (fp32), big MFMA GEMM
//   h_t = tanh(h_{t-1} @ Wh + xw_t) -> overwrites d_out in place
//
// rnn_scan v7 (round-7 lesson: 1 wave/SIMD exposes all latency; ~55% stall):
//  8 waves/block = 2 waves/SIMD so stalls of one wave are filled by the other.
//  Fits the 256-reg budget via v6's swapped-operand layout, halved per wave:
//   wave w owns 64 cols (cc = 4w..4w+3): bw = 12 kk x 4 cc = 192 regs,
//   acc 16, xwv 16, ~15 addr/temps -> ~250 regs.
//  kk 12..15 from 128 KB LDS (16 b128 reads/wave/step), h ping-pong 2x16 KB.
//  Same per-step structure as v6: acc init from xw, xw(t+1) prefetch at top,
//  imm-offset LDS addressing, vector epilogue (cvt_pk_bf16 + b64 writes),
//  ONE raw s_barrier + lgkmcnt(0) per step. Same kk order -> same absmax.

typedef __attribute__((ext_vector_type(8))) short short8;
typedef __attribute__((ext_vector_type(4))) float f32x4;

#define DIM 512
#define T_S 512

union Frag { uint4 v; short8 s; unsigned short u[8]; };

static __device__ __forceinline__ unsigned short f2bf(float f) {
  union { float f; unsigned u; } v;
  v.f = f;
  unsigned r = v.u + 0x7FFFu + ((v.u >> 16) & 1u);
  return (unsigned short)(r >> 16);
}

static __device__ __forceinline__ unsigned cvt_pk_bf16(float a, float b) {
  unsigned r;
  asm("v_cvt_pk_bf16_f32 %0, %1, %2" : "=v"(r) : "v"(a), "v"(b));
  return r;  // lo16 = bf16(a), hi16 = bf16(b), RNE
}

static __device__ __forceinline__ float fast_tanh(float s) {
  float e = __builtin_amdgcn_exp2f(2.885390082f * s);
  return 1.0f - 2.0f * __builtin_amdgcn_rcpf(e + 1.0f);
}

// ---------------------------------------------------------------------------
// Pack W (512x512 fp32) into bf16 MFMA fragments (A/B-symmetric layout).
// Frag (kk, cc): lane l holds W[k=32kk+8(l>>4)+j][col=16cc+(l&15)], j=0..7,
// at dst[(kk*32+cc)*64 + lane].
// ---------------------------------------------------------------------------
__global__ __launch_bounds__(64) void prepack(const float* __restrict__ Wx,
                                              const float* __restrict__ Wh,
                                              uint4* __restrict__ wxb,
                                              uint4* __restrict__ whb) {
  int bid = blockIdx.x;
  int mat = bid >> 9;
  int idx = bid & 511;
  int kk = idx >> 5, cc = idx & 31;
  int lane = threadIdx.x;
  int lo = lane & 15, hi = lane >> 4;
  const float* src = mat ? Wh : Wx;
  uint4* dst = mat ? whb : wxb;
  int col = cc * 16 + lo;
  int kbase = kk * 32 + hi * 8;
  Frag fr;
#pragma unroll
  for (int j = 0; j < 8; ++j)
    fr.u[j] = f2bf(src[(size_t)(kbase + j) * DIM + col]);
  dst[(kk * 32 + cc) * 64 + lane] = fr.v;
}

// ---------------------------------------------------------------------------
// xw = x @ Wx + b -> out (fp32). M=32768, K=N=512. Unchanged.
// ---------------------------------------------------------------------------
__global__ __launch_bounds__(256) void gemm_xw(const float* __restrict__ x,
                                               const uint4* __restrict__ wxb,
                                               const float* __restrict__ bias,
                                               float* __restrict__ out) {
  int bid = blockIdx.x;
  int m = bid >> 2, nb = bid & 3;
  int wave = threadIdx.x >> 6, lane = threadIdx.x & 63;
  int lo = lane & 15, hi = lane >> 4;
  int rowbase = m * 64;
  int colbase = nb * 128 + wave * 32;

  f32x4 acc[4][2];
#pragma unroll
  for (int mi = 0; mi < 4; ++mi)
#pragma unroll
    for (int ni = 0; ni < 2; ++ni) acc[mi][ni] = (f32x4){0.f, 0.f, 0.f, 0.f};

  for (int kk = 0; kk < 16; ++kk) {
    short8 afrag[4];
#pragma unroll
    for (int mi = 0; mi < 4; ++mi) {
      const float* ap = x + (size_t)(rowbase + mi * 16 + lo) * DIM + kk * 32 + hi * 8;
      float4 f0 = *(const float4*)ap;
      float4 f1 = *(const float4*)(ap + 4);
      Frag a;
      a.u[0] = f2bf(f0.x); a.u[1] = f2bf(f0.y); a.u[2] = f2bf(f0.z); a.u[3] = f2bf(f0.w);
      a.u[4] = f2bf(f1.x); a.u[5] = f2bf(f1.y); a.u[6] = f2bf(f1.z); a.u[7] = f2bf(f1.w);
      afrag[mi] = a.s;
    }
#pragma unroll
    for (int ni = 0; ni < 2; ++ni) {
      int cc = nb * 8 + wave * 2 + ni;
      Frag b;
      b.v = wxb[(kk * 32 + cc) * 64 + lane];
#pragma unroll
      for (int mi = 0; mi < 4; ++mi)
        acc[mi][ni] = __builtin_amdgcn_mfma_f32_16x16x32_bf16(afrag[mi], b.s, acc[mi][ni], 0, 0, 0);
    }
  }
#pragma unroll
  for (int ni = 0; ni < 2; ++ni) {
    int col = colbase + ni * 16 + lo;
    float bv = bias[col];
#pragma unroll
    for (int mi = 0; mi < 4; ++mi)
#pragma unroll
      for (int r = 0; r < 4; ++r) {
        int row = rowbase + mi * 16 + hi * 4 + r;
        out[(size_t)row * DIM + col] = acc[mi][ni][r] + bv;
      }
  }
}

// ---------------------------------------------------------------------------
// Recurrent scan v7. grid = 4 blocks x 512 thr (8 waves, 2/SIMD).
// Block g: batch rows [16g,16g+16), all 512 cols. Wave w: cols [64w,64w+64).
// h in LDS as [buf][n][k] bf16, XOR-swizzled: byte = n*1024 + ((k*2)^((n&7)<<4)).
// ---------------------------------------------------------------------------
__shared__ uint4 wlds[4][32][64];             // 128 KB: Wh kk=12..15
__shared__ unsigned short hbuf2[2][16 * 512]; // 32 KB ping/pong

template <int BUF>
static __device__ __forceinline__ void step_body(
    int t, int w, int lane, const uint4 (&bw)[12][4],
    const uint4* const (&rdp)[8], uint2* const (&wrp)[4],
    float (&xwv)[16], float*& gp) {
  // acc starts at xw (lane: n=lo, cols 64w + 16i + 4hi + r)
  f32x4 acc[4];
#pragma unroll
  for (int i = 0; i < 4; ++i)
    acc[i] = (f32x4){xwv[i * 4 + 0], xwv[i * 4 + 1], xwv[i * 4 + 2], xwv[i * 4 + 3]};

  // prefetch xw(t+1): 4x dwordx4, issued before MFMA phase
  const float* lp = gp + ((t < T_S - 1) ? DIM : 0);
#pragma unroll
  for (int i = 0; i < 4; ++i) {
    float4 f = *(const float4*)(lp + i * 16);
    xwv[i * 4 + 0] = f.x; xwv[i * 4 + 1] = f.y;
    xwv[i * 4 + 2] = f.z; xwv[i * 4 + 3] = f.w;
  }

  // kk 0..11: register-resident weights as A; h frag as B (imm-offset reads)
#pragma unroll
  for (int kk = 0; kk < 12; ++kk) {
    Frag hf; hf.v = rdp[kk & 7][((kk & 8) ? 32 : 0) + BUF * 1024];
#pragma unroll
    for (int i = 0; i < 4; ++i) {
      Frag a; a.v = bw[kk][i];
      acc[i] = __builtin_amdgcn_mfma_f32_16x16x32_bf16(a.s, hf.s, acc[i], 0, 0, 0);
    }
  }
  // kk 12..15: LDS-resident weights
#pragma unroll
  for (int kk = 12; kk < 16; ++kk) {
    Frag hf; hf.v = rdp[kk & 7][32 + BUF * 1024];
#pragma unroll
    for (int i = 0; i < 4; ++i) {
      Frag a; a.v = wlds[kk - 12][w * 4 + i][lane];
      acc[i] = __builtin_amdgcn_mfma_f32_16x16x32_bf16(a.s, hf.s, acc[i], 0, 0, 0);
    }
  }

  // epilogue: lane owns n=lo, 4 consecutive cols per acc group
#pragma unroll
  for (int i = 0; i < 4; ++i) {
    float h0 = fast_tanh(acc[i][0]);
    float h1 = fast_tanh(acc[i][1]);
    float h2 = fast_tanh(acc[i][2]);
    float h3 = fast_tanh(acc[i][3]);
    *(float4*)(gp + i * 16) = (float4){h0, h1, h2, h3};   // out row n, 16B
    uint2 u;
    u.x = cvt_pk_bf16(h0, h1);
    u.y = cvt_pk_bf16(h2, h3);
    wrp[i][(BUF ^ 1) * 2048] = u;                          // ds_write_b64
  }
  gp += DIM;

  // one barrier per step: LDS h-writes visible; no vmem drain
  asm volatile("s_waitcnt lgkmcnt(0)" ::: "memory");
  __builtin_amdgcn_sched_barrier(0);
  __builtin_amdgcn_s_barrier();
  __builtin_amdgcn_sched_barrier(0);
}

__global__ __launch_bounds__(512, 2) void rnn_scan(const float* __restrict__ h0,
                                                   const uint4* __restrict__ whb,
                                                   float* __restrict__ out) {
  int g = blockIdx.x;
  int w = threadIdx.x >> 6, lane = threadIdx.x & 63;
  int lo = lane & 15, hi = lane >> 4;
  int msk = (lo & 7) << 4;

  // register-resident Wh: kk 0..11 x this wave's 4 col-tiles = 192 regs
  uint4 bw[12][4];
#pragma unroll
  for (int kk = 0; kk < 12; ++kk)
#pragma unroll
    for (int i = 0; i < 4; ++i)
      bw[kk][i] = whb[(kk * 32 + (w * 4 + i)) * 64 + lane];

  // LDS-resident Wh: kk 12..15, all 32 cc (coalesced cooperative stage)
#pragma unroll
  for (int e = 0; e < 16; ++e) {
    int idx = e * 512 + threadIdx.x;
    int s = idx >> 11, rem = idx & 2047;
    wlds[s][rem >> 6][rem & 63] = whb[((12 + s) * 32 + (rem >> 6)) * 64 + (rem & 63)];
  }

  // loop-invariant LDS addresses (buffer 0 bases; +16384B via imm for buffer 1)
  // read (B=h frag): byte = lo*1024 + ((kk*64 + hi*16) ^ msk), kk=0..7
  const uint4* rdp[8];
#pragma unroll
  for (int kk = 0; kk < 8; ++kk)
    rdp[kk] = (const uint4*)((const char*)hbuf2 + lo * 1024 + ((kk * 64 + hi * 16) ^ msk));
  // write: byte = lo*1024 + (((64w + 16i + 4hi)*2) ^ msk), i=0..3 bases
  uint2* wrp[4];
#pragma unroll
  for (int i = 0; i < 4; ++i)
    wrp[i] = (uint2*)((char*)hbuf2 + lo * 1024 + ((128 * w + 32 * i + 8 * hi) ^ msk));

  // h_0 into buffer 0: lane loads h0[n=lo][c..c+3], packs, b64-writes
#pragma unroll
  for (int i = 0; i < 4; ++i) {
    const float* hp = h0 + (size_t)(g * 16 + lo) * DIM + w * 64 + i * 16 + hi * 4;
    float4 f = *(const float4*)hp;
    uint2 u;
    u.x = (unsigned)f2bf(f.x) | ((unsigned)f2bf(f.y) << 16);
    u.y = (unsigned)f2bf(f.z) | ((unsigned)f2bf(f.w) << 16);
    wrp[i][0] = u;
  }

  // running global pointer: lane -> out[n=16g+lo][t=0][64w + 4hi]
  float* gp = out + ((size_t)(g * 16 + lo) * T_S) * DIM + w * 64 + hi * 4;

  // prime xw for t=0
  float xwv[16];
#pragma unroll
  for (int i = 0; i < 4; ++i) {
    float4 f = *(const float4*)(gp + i * 16);
    xwv[i * 4 + 0] = f.x; xwv[i * 4 + 1] = f.y;
    xwv[i * 4 + 2] = f.z; xwv[i * 4 + 3] = f.w;
  }

  __syncthreads();  // heavy barrier once before the loop

#pragma unroll 1
  for (int t = 0; t < T_S; t += 2) {
    step_body<0>(t,     w, lane, bw, rdp, wrp, xwv, gp);
    step_body<1>(t + 1, w, lane, bw, rdp, wrp, xwv, gp);
  }
}

// ---------------------------------------------------------------------------
extern "C" void kernel_launch(void* const* d_in, const int* in_sizes, int n_in,
                              void* d_out, int out_size, void* d_ws, size_t ws_size,
                              hipStream_t stream) {
  const float* x  = (const float*)d_in[0];
  const float* h0 = (const float*)d_in[1];
  const float* Wx = (const float*)d_in[2];
  const float* Wh = (const float*)d_in[3];
  const float* b  = (const float*)d_in[4];
  float* out = (float*)d_out;

  char* ws = (char*)d_ws;
  uint4* whb = (uint4*)ws;                  // 512 KB
  uint4* wxb = (uint4*)(ws + 524288);       // 512 KB

  prepack<<<1024, 64, 0, stream>>>(Wx, Wh, wxb, whb);
  gemm_xw<<<2048, 256, 0, stream>>>(x, wxb, b, out);
  rnn_scan<<<4, 512, 0, stream>>>(h0, whb, out);
}